// Round 20
// baseline (350.750 us; speedup 1.0000x reference)
//
#include <hip/hip_runtime.h>

#define T_    1024
#define H_    2048
#define NH_   16
#define NKV_  4
#define HD_   128
#define E_    16
#define I_    768
#define QKVN  3072

typedef __attribute__((ext_vector_type(8))) short  short8;
typedef __attribute__((ext_vector_type(4))) float  f32x4;
typedef unsigned short u16;

__device__ inline u16 f2bf(float f) {
  unsigned u = __builtin_bit_cast(unsigned, f);
  return (u16)((u + 0x7fffu + ((u >> 16) & 1u)) >> 16);
}
__device__ inline float bf2f(u16 h) {
  unsigned u = ((unsigned)h) << 16;
  return __builtin_bit_cast(float, u);
}

// async global->LDS, 16B/lane. LDS dest = wave-uniform base + lane*16 (m104).
__device__ inline void gll16(const u16* g, u16* l) {
  __builtin_amdgcn_global_load_lds(
      (const __attribute__((address_space(1))) void*)g,
      (__attribute__((address_space(3))) void*)l, 16, 0, 0);
}
__device__ inline void gll16f(const float* g, float* l) {
  __builtin_amdgcn_global_load_lds(
      (const __attribute__((address_space(1))) void*)g,
      (__attribute__((address_space(3))) void*)l, 16, 0, 0);
}

__device__ inline float blk_sum(float v, float* lds) {
#pragma unroll
  for (int o = 32; o; o >>= 1) v += __shfl_down(v, o);
  int w = threadIdx.x >> 6;
  __syncthreads();
  if ((threadIdx.x & 63) == 0) lds[w] = v;
  __syncthreads();
  float s = lds[0];
  int nw = blockDim.x >> 6;
  for (int i = 1; i < nw; ++i) s += lds[i];
  return s;
}

// ---- GEMM: 512 threads, 8 waves (4M x 2N), tile 128 x 64 x 32 ----
// r19->r20: r18's deep gll pipeline (counted vmcnt, loads never drained in
// steady state; zero staging VGPRs -> spill-proof) COMBINED with r15's fast
// b128 fragment path via a cheap once-per-tile convert pass (r18's null was
// the per-fragment fp32->bf16 scalar ds_read path saturating the LDS pipe,
// NOT the pipeline). 4 A buffers (bf16 linear [128][32]), 4 B fp32 buffers
// ([32][64] as-loaded), 1 padded bf16 B buffer [64][40] rebuilt per tile.

template<int SA, int SB>
__device__ inline void mma2(const u16* As, const u16* Bs, f32x4 acc[2][2]) {
  const int lane = threadIdx.x & 63, wv = threadIdx.x >> 6;
  const int wr = wv >> 1, wc = wv & 1;
  const int kk = (lane >> 4) * 8, rr = lane & 15;
  short8 aF[2], bF[2];
#pragma unroll
  for (int m = 0; m < 2; ++m)
    aF[m] = *(const short8*)(As + (wr * 32 + m * 16 + rr) * SA + kk);
#pragma unroll
  for (int n = 0; n < 2; ++n)
    bF[n] = *(const short8*)(Bs + (wc * 32 + n * 16 + rr) * SB + kk);
#pragma unroll
  for (int m = 0; m < 2; ++m)
#pragma unroll
    for (int n = 0; n < 2; ++n)
      acc[m][n] = __builtin_amdgcn_mfma_f32_16x16x32_bf16(aF[m], bF[n], acc[m][n], 0, 0, 0);
}

#define ZERO_ACC(acc) do { \
  _Pragma("unroll") for (int m_ = 0; m_ < 2; ++m_) \
  _Pragma("unroll") for (int n_ = 0; n_ < 2; ++n_) acc[m_][n_] = (f32x4){0.f,0.f,0.f,0.f}; \
} while (0)

#define EPI_ROW(m, r)  (((threadIdx.x >> 6) >> 1) * 32 + (m)*16 + (((threadIdx.x&63) >> 4) * 4) + (r))
#define EPI_COL(n)     ((((threadIdx.x >> 6) & 1) * 32) + (n)*16 + ((threadIdx.x&63) & 15))

// One pipeline step for tile t using static buffer slot (As, Fs).
// Invariant at entry: glls for tiles t..t+3 issued (8 per thread outstanding max).
template<class IA, class IB>
__device__ inline void step4g(IA& ia, IB& ib, int t, int NT,
                              u16* As, float* Fs, u16* Bb, f32x4 acc[2][2]) {
  int rem = NT - 1 - t;
  if (rem >= 3)      asm volatile("s_waitcnt vmcnt(6)" ::: "memory");
  else if (rem == 2) asm volatile("s_waitcnt vmcnt(4)" ::: "memory");
  else if (rem == 1) asm volatile("s_waitcnt vmcnt(2)" ::: "memory");
  else               asm volatile("s_waitcnt vmcnt(0)" ::: "memory");
  __builtin_amdgcn_s_barrier();                 // tile t landed for all waves
  {                                             // convert Fs[32][64] -> Bb[64][40]
    int cn = threadIdx.x & 63, ck = (threadIdx.x >> 6) * 4;
    float f0 = Fs[(ck + 0) * 64 + cn];
    float f1 = Fs[(ck + 1) * 64 + cn];
    float f2 = Fs[(ck + 2) * 64 + cn];
    float f3 = Fs[(ck + 3) * 64 + cn];
    uint2 w;
    w.x = (unsigned)f2bf(f0) | ((unsigned)f2bf(f1) << 16);
    w.y = (unsigned)f2bf(f2) | ((unsigned)f2bf(f3) << 16);
    *(uint2*)(Bb + cn * 40 + ck) = w;
  }
  asm volatile("s_waitcnt lgkmcnt(0)" ::: "memory");
  __builtin_amdgcn_s_barrier();                 // Bb ready
  mma2<32, 40>(As, Bb, acc);                    // consume tile t
  asm volatile("" ::: "memory");
  __builtin_amdgcn_s_barrier();                 // all waves done reading As/Bb
  asm volatile("" ::: "memory");
  if (t + 4 < NT) { ia(As, t + 4); ib(Fs, t + 4); }
}

// NT % 4 == 0, NT >= 4.
template<int NT, class IA, class IB>
__device__ inline void pipe4g(IA ia, IB ib,
                              u16* A0, u16* A1, u16* A2, u16* A3,
                              float* F0, float* F1, float* F2, float* F3,
                              u16* Bb, f32x4 acc[2][2]) {
  ia(A0, 0); ib(F0, 0);
  ia(A1, 1); ib(F1, 1);
  ia(A2, 2); ib(F2, 2);
  ia(A3, 3); ib(F3, 3);
#pragma unroll 1
  for (int t = 0; t < NT; t += 4) {
    step4g(ia, ib, t,     NT, A0, F0, Bb, acc);
    step4g(ia, ib, t + 1, NT, A1, F1, Bb, acc);
    step4g(ia, ib, t + 2, NT, A2, F2, Bb, acc);
    step4g(ia, ib, t + 3, NT, A3, F3, Bb, acc);
  }
}

#define GEMM_LDS \
  __shared__ __align__(16) u16 A0[128 * 32], A1[128 * 32], A2[128 * 32], A3[128 * 32]; \
  __shared__ __align__(16) float F0[32 * 64], F1[32 * 64], F2[32 * 64], F3[32 * 64]; \
  __shared__ __align__(16) u16 Bb[64 * 40];

// ---------------- kernels ----------------

__global__ __launch_bounds__(256) void k_rms1(const float* x, const float* w, u16* out) {
  __shared__ float lds[4];
  int t = blockIdx.x, tid = threadIdx.x;
  float v[8]; float ss = 0.f;
#pragma unroll
  for (int i = 0; i < 8; ++i) { v[i] = x[(size_t)t * H_ + tid + 256 * i]; ss += v[i] * v[i]; }
  ss = blk_sum(ss, lds);
  float inv = rsqrtf(ss * (1.f / H_) + 1e-6f);
#pragma unroll
  for (int i = 0; i < 8; ++i)
    out[(size_t)t * H_ + tid + 256 * i] = f2bf(v[i] * inv * w[tid + 256 * i]);
}

__global__ __launch_bounds__(256) void k_rms2(const float* x, const float* w,
                                              float* outf, u16* outb) {
  __shared__ float lds[4];
  int t = blockIdx.x, tid = threadIdx.x;
  float v[8]; float ss = 0.f;
#pragma unroll
  for (int i = 0; i < 8; ++i) { v[i] = x[(size_t)t * H_ + tid + 256 * i]; ss += v[i] * v[i]; }
  ss = blk_sum(ss, lds);
  float inv = rsqrtf(ss * (1.f / H_) + 1e-6f);
#pragma unroll
  for (int i = 0; i < 8; ++i) {
    float r = v[i] * inv * w[tid + 256 * i];
    outf[(size_t)t * H_ + tid + 256 * i] = r;
    outb[(size_t)t * H_ + tid + 256 * i] = f2bf(r);
  }
}

// qkv: [1024 x 3072 x 2048]. grid (48, 8), NT=64
__global__ __launch_bounds__(512) void k_qkv(const u16* h1, const float* wqkv, float* qkv) {
  GEMM_LDS
  int bn = blockIdx.x, bm = blockIdx.y, tid = threadIdx.x;
  f32x4 acc[2][2]; ZERO_ACC(acc);
  auto ia = [&](u16* As, int kt) {
    gll16(h1 + (size_t)(bm * 128 + (tid >> 2)) * H_ + kt * 32 + (tid & 3) * 8,
          As + (tid & 448) * 8);
  };
  auto ib = [&](float* Bf, int kt) {
    gll16f(wqkv + (size_t)(kt * 32 + (tid >> 4)) * QKVN + bn * 64 + (tid & 15) * 4,
           Bf + (tid & 448) * 4);
  };
  pipe4g<H_ / 32>(ia, ib, A0, A1, A2, A3, F0, F1, F2, F3, Bb, acc);
#pragma unroll
  for (int m = 0; m < 2; ++m)
#pragma unroll
    for (int n = 0; n < 2; ++n) {
      f32x4 a = acc[m][n];
#pragma unroll
      for (int r = 0; r < 4; ++r)
        qkv[(size_t)(bm * 128 + EPI_ROW(m, r)) * QKVN + bn * 64 + EPI_COL(n)] = a[r];
    }
}

__global__ __launch_bounds__(256) void k_qkrope(const float* qkv, const int* pos,
                                                const float* wq, const float* wk,
                                                u16* q, u16* kk, u16* vT) {
  __shared__ float cs[64], sn[64];
  int t = blockIdx.x, tid = threadIdx.x, lane = tid & 63, w = tid >> 6;
  if (tid < 64) {
    float fr = expf(-((float)tid / 64.f) * 9.210340371976184f);
    float ang = (float)pos[t] * fr;
    float s_, c_; sincosf(ang, &s_, &c_);
    cs[tid] = c_; sn[tid] = s_;
  }
  __syncthreads();
  const float* row = qkv + (size_t)t * QKVN;
  for (int h = w; h < NH_; h += 4) {
    float x1 = row[h * 128 + lane], x2 = row[h * 128 + 64 + lane];
    float ss = x1 * x1 + x2 * x2;
#pragma unroll
    for (int o = 32; o; o >>= 1) ss += __shfl_down(ss, o);
    ss = __shfl(ss, 0);
    float inv = rsqrtf(ss * (1.f / HD_) + 1e-6f);
    float n1 = x1 * inv * wq[lane], n2 = x2 * inv * wq[64 + lane];
    float o1 = n1 * cs[lane] - n2 * sn[lane];
    float o2 = n2 * cs[lane] + n1 * sn[lane];
    q[(size_t)t * (NH_ * HD_) + h * 128 + lane] = f2bf(o1);
    q[(size_t)t * (NH_ * HD_) + h * 128 + 64 + lane] = f2bf(o2);
  }
  if (w < NKV_) {
    int h = w;
    float x1 = row[2048 + h * 128 + lane], x2 = row[2048 + h * 128 + 64 + lane];
    float ss = x1 * x1 + x2 * x2;
#pragma unroll
    for (int o = 32; o; o >>= 1) ss += __shfl_down(ss, o);
    ss = __shfl(ss, 0);
    float inv = rsqrtf(ss * (1.f / HD_) + 1e-6f);
    float n1 = x1 * inv * wk[lane], n2 = x2 * inv * wk[64 + lane];
    float o1 = n1 * cs[lane] - n2 * sn[lane];
    float o2 = n2 * cs[lane] + n1 * sn[lane];
    kk[((size_t)h * T_ + t) * HD_ + lane] = f2bf(o1);
    kk[((size_t)h * T_ + t) * HD_ + 64 + lane] = f2bf(o2);
    float v1 = row[2560 + h * 128 + lane], v2 = row[2560 + h * 128 + 64 + lane];
    vT[((size_t)(h * 128 + lane)) * T_ + t] = f2bf(v1);
    vT[((size_t)(h * 128 + 64 + lane)) * T_ + t] = f2bf(v2);
  }
}

// Fused attention with kv-split x4 (r17/r19-proven).
__global__ __launch_bounds__(256) void k_fattn(const u16* q, const u16* kb,
                                               const u16* vT, float* opart, float* lpart) {
  __shared__ __align__(16) u16 Ks[64 * 136];
  __shared__ __align__(16) u16 Vs[128 * 72];
  __shared__ __align__(16) u16 Ps[4 * 16 * 72];
  int h = blockIdx.x, qt = blockIdx.y, kvs = blockIdx.z;
  int tid = threadIdx.x, lane = tid & 63, wv = tid >> 6;
  int rr = lane & 15, kk = (lane >> 4) * 8;
  const u16* kbh = kb + (size_t)(h >> 2) * T_ * HD_;
  const u16* vTh = vT + (size_t)(h >> 2) * HD_ * T_;
  int q0 = qt * 64 + wv * 16;
  short8 qf[4];
#pragma unroll
  for (int ks = 0; ks < 4; ++ks)
    qf[ks] = *(const short8*)(q + (size_t)(q0 + rr) * (NH_ * HD_) + h * 128 + ks * 32 + kk);
  f32x4 oacc[8];
#pragma unroll
  for (int i = 0; i < 8; ++i) oacc[i] = (f32x4){0.f, 0.f, 0.f, 0.f};
  float lsum[4] = {0.f, 0.f, 0.f, 0.f};
  const float scale = 0.08838834764831845f;
  u16* Pw = Ps + wv * 16 * 72;
#pragma unroll 1
  for (int kv = kvs * 4; kv < kvs * 4 + 4; ++kv) {
    __syncthreads();
    {
      uint4 kreg[4];
#pragma unroll
      for (int i = 0; i < 4; ++i) {
        int c = tid + 256 * i;
        kreg[i] = *(const uint4*)(kbh + (size_t)(kv * 64 + (c >> 4)) * HD_ + (c & 15) * 8);
      }
#pragma unroll
      for (int i = 0; i < 4; ++i) {
        int c = tid + 256 * i;
        *(uint4*)(Ks + (c >> 4) * 136 + (c & 15) * 8) = kreg[i];
      }
    }
    {
      uint4 vreg[4];
#pragma unroll
      for (int i = 0; i < 4; ++i) {
        int c = tid + 256 * i;
        vreg[i] = *(const uint4*)(vTh + (size_t)(c >> 3) * T_ + kv * 64 + (c & 7) * 8);
      }
#pragma unroll
      for (int i = 0; i < 4; ++i) {
        int c = tid + 256 * i;
        *(uint4*)(Vs + (c >> 3) * 72 + (c & 7) * 8) = vreg[i];
      }
    }
    __syncthreads();
    f32x4 sacc[4];
#pragma unroll
    for (int nf = 0; nf < 4; ++nf) sacc[nf] = (f32x4){0.f, 0.f, 0.f, 0.f};
#pragma unroll
    for (int ks = 0; ks < 4; ++ks)
#pragma unroll
      for (int nf = 0; nf < 4; ++nf) {
        short8 bF = *(const short8*)(Ks + (nf * 16 + rr) * 136 + ks * 32 + kk);
        sacc[nf] = __builtin_amdgcn_mfma_f32_16x16x32_bf16(qf[ks], bF, sacc[nf], 0, 0, 0);
      }
#pragma unroll
    for (int nf = 0; nf < 4; ++nf)
#pragma unroll
      for (int r = 0; r < 4; ++r) {
        float p = __expf(sacc[nf][r] * scale);
        lsum[r] += p;
        Pw[((lane >> 4) * 4 + r) * 72 + nf * 16 + rr] = f2bf(p);
      }
#pragma unroll
    for (int ks2 = 0; ks2 < 2; ++ks2) {
      short8 pa = *(const short8*)(Pw + rr * 72 + ks2 * 32 + kk);
#pragma unroll
      for (int nd = 0; nd < 8; ++nd) {
        short8 bV = *(const short8*)(Vs + (nd * 16 + rr) * 72 + ks2 * 32 + kk);
        oacc[nd] = __builtin_amdgcn_mfma_f32_16x16x32_bf16(pa, bV, oacc[nd], 0, 0, 0);
      }
    }
  }
#pragma unroll
  for (int r = 0; r < 4; ++r) {
#pragma unroll
    for (int o = 1; o < 16; o <<= 1) lsum[r] += __shfl_xor(lsum[r], o);
  }
  if ((lane & 15) == 0) {
#pragma unroll
    for (int r = 0; r < 4; ++r)
      lpart[((size_t)kvs * NH_ + h) * T_ + q0 + (lane >> 4) * 4 + r] = lsum[r];
  }
  float* op = opart + (size_t)kvs * T_ * (NH_ * HD_);
#pragma unroll
  for (int nd = 0; nd < 8; ++nd)
#pragma unroll
    for (int r = 0; r < 4; ++r)
      op[(size_t)(q0 + (lane >> 4) * 4 + r) * (NH_ * HD_) + h * 128 + nd * 16 + rr] =
          oacc[nd][r];
}

__global__ __launch_bounds__(256) void k_attnfin(const float* opart, const float* lpart,
                                                 u16* ctx) {
  int t = blockIdx.x, tid = threadIdx.x;
#pragma unroll
  for (int i = 0; i < 8; ++i) {
    int idx = tid + 256 * i;
    int h = idx >> 7;
    float l = 0.f, o = 0.f;
#pragma unroll
    for (int s = 0; s < 4; ++s) {
      l += lpart[((size_t)s * NH_ + h) * T_ + t];
      o += opart[(size_t)s * T_ * (NH_ * HD_) + (size_t)t * (NH_ * HD_) + idx];
    }
    ctx[(size_t)t * (NH_ * HD_) + idx] = f2bf(o / l);
  }
}

// wo: [1024 x 2048 x 2048]. grid (32, 8), NT=64
__global__ __launch_bounds__(512) void k_wo(const u16* ctx, const float* wo,
                                            const float* hs, float* resid) {
  GEMM_LDS
  int bn = blockIdx.x, bm = blockIdx.y, tid = threadIdx.x;
  f32x4 acc[2][2]; ZERO_ACC(acc);
  auto ia = [&](u16* As, int kt) {
    gll16(ctx + (size_t)(bm * 128 + (tid >> 2)) * H_ + kt * 32 + (tid & 3) * 8,
          As + (tid & 448) * 8);
  };
  auto ib = [&](float* Bf, int kt) {
    gll16f(wo + (size_t)(kt * 32 + (tid >> 4)) * H_ + bn * 64 + (tid & 15) * 4,
           Bf + (tid & 448) * 4);
  };
  pipe4g<H_ / 32>(ia, ib, A0, A1, A2, A3, F0, F1, F2, F3, Bb, acc);
#pragma unroll
  for (int m = 0; m < 2; ++m)
#pragma unroll
    for (int n = 0; n < 2; ++n) {
      f32x4 a = acc[m][n];
#pragma unroll
      for (int r = 0; r < 4; ++r) {
        size_t idx = (size_t)(bm * 128 + EPI_ROW(m, r)) * H_ + bn * 64 + EPI_COL(n);
        resid[idx] = a[r] + hs[idx];
      }
    }
}

__global__ __launch_bounds__(256) void k_router(const float* h2f, const float* wr_,
                                                int* topi, float* topw, int* cnt) {
  __shared__ float xs[H_];
  __shared__ float red[4][16];
  __shared__ float lg[16];
  int t = blockIdx.x, tid = threadIdx.x;
#pragma unroll
  for (int i = 0; i < 8; ++i) xs[tid + 256 * i] = h2f[(size_t)t * H_ + tid + 256 * i];
  __syncthreads();
  int e = tid & 15, p = tid >> 4;
  float s = 0.f;
  int b0 = p * 128;
  for (int i = 0; i < 128; ++i) s += xs[b0 + i] * wr_[(size_t)(b0 + i) * E_ + e];
  s += __shfl_down(s, 32);
  s += __shfl_down(s, 16);
  int lane = tid & 63, w = tid >> 6;
  if (lane < 16) red[w][lane] = s;
  __syncthreads();
  if (tid < 16) lg[tid] = red[0][tid] + red[1][tid] + red[2][tid] + red[3][tid];
  __syncthreads();
  if (tid == 0) {
    float l1 = -1e30f; int e1 = 0;
    for (int i = 0; i < E_; ++i) if (lg[i] > l1) { l1 = lg[i]; e1 = i; }
    float l2 = -1e30f; int e2 = 0;
    for (int i = 0; i < E_; ++i) if (i != e1 && lg[i] > l2) { l2 = lg[i]; e2 = i; }
    float d = __expf(l2 - l1);
    float w1 = 1.f / (1.f + d), w2 = d / (1.f + d);
    topi[2 * t] = e1; topi[2 * t + 1] = e2;
    topw[2 * t] = w1; topw[2 * t + 1] = w2;
    atomicAdd(&cnt[e1], 1);
    atomicAdd(&cnt[e2], 1);
  }
}

__global__ void k_scan(const int* cnt, int* basearr) {
  if (threadIdx.x == 0) {
    int b = 0;
    for (int e = 0; e < E_; ++e) { basearr[e] = b; b += cnt[e]; }
    basearr[E_] = b;
  }
}

__global__ __launch_bounds__(256) void k_assign(const int* topi, const float* topw,
                                                const int* basearr, int* posc,
                                                int* tok, float* wslot) {
  int t = blockIdx.x * 256 + threadIdx.x;
  if (t < T_) {
#pragma unroll
    for (int j = 0; j < 2; ++j) {
      int e = topi[2 * t + j];
      int p = atomicAdd(&posc[e], 1);
      int s = basearr[e] + p;
      tok[s] = t;
      wslot[s] = topw[2 * t + j];
    }
  }
}

// gateup: 128 tokens x 32 out cols (64-col interleaved g|u panel per 16-col
// group; acc[m][0]=gate, acc[m][1]=up in the SAME lane). grid (16,24,8), NT=64.
__global__ __launch_bounds__(512) void k_gateup(const u16* h2b,
                                                const float* wg, const float* wu,
                                                const int* cnt, const int* basearr, const int* tok,
                                                u16* act) {
  GEMM_LDS
  __shared__ int gat_s[128];
  int e = blockIdx.x;
  int c = cnt[e];
  int mt = blockIdx.z;
  if (mt * 128 >= c) return;
  int basee = basearr[e];
  int gmax = c - mt * 128;
  int n0 = blockIdx.y * 32;
  int tid = threadIdx.x;
  if (tid < 128) {
    int r = mt * 128 + tid;
    gat_s[tid] = (r < c) ? tok[basee + r] : tok[basee];
  }
  __syncthreads();
  int grow = gat_s[tid >> 2];
  const float* Bg = wg + (size_t)e * H_ * I_;
  const float* Bu = wu + (size_t)e * H_ * I_;
  f32x4 acc[2][2]; ZERO_ACC(acc);
  auto ia = [&](u16* As, int kt) {
    gll16(h2b + (size_t)grow * H_ + kt * 32 + (tid & 3) * 8, As + (tid & 448) * 8);
  };
  auto ib = [&](float* Bf, int kt) {
    int n4 = (tid & 15) * 4;
    int fn = n4 >> 4;                         // 0..3
    const float* base = (fn & 1) ? Bu : Bg;
    int col = n0 + (fn >> 1) * 16 + (n4 & 15);
    gll16f(base + (size_t)(kt * 32 + (tid >> 4)) * I_ + col, Bf + (tid & 448) * 4);
  };
  pipe4g<H_ / 32>(ia, ib, A0, A1, A2, A3, F0, F1, F2, F3, Bb, acc);
  int slot0 = basee + mt * 128;
  int col = n0 + ((tid >> 6) & 1) * 16 + ((tid & 63) & 15);
#pragma unroll
  for (int m = 0; m < 2; ++m) {
#pragma unroll
    for (int r = 0; r < 4; ++r) {
      int row = EPI_ROW(m, r);
      if (row >= gmax) continue;
      float g = acc[m][0][r], u = acc[m][1][r];
      float sg = g / (1.f + __expf(-g));
      act[(size_t)(slot0 + row) * I_ + col] = f2bf(sg * u);
    }
  }
}

// down: [slots x 2048 x 768]. grid (32, 16, 8), NT=24
__global__ __launch_bounds__(512) void k_down(const u16* act, const float* wd,
                                              const int* cnt, const int* basearr,
                                              const int* tok, const float* wslot,
                                              float* moe) {
  GEMM_LDS
  int e = blockIdx.y;
  int c = cnt[e];
  int mt = blockIdx.z;
  if (mt * 128 >= c) return;
  int basee = basearr[e];
  int gmax = c - mt * 128;
  int slot0 = basee + mt * 128;
  int n0 = blockIdx.x * 64;
  int tid = threadIdx.x;
  const u16* Ap = act + (size_t)slot0 * I_;
  const float* Bp = wd + (size_t)e * I_ * H_;
  f32x4 acc[2][2]; ZERO_ACC(acc);
  auto ia = [&](u16* As, int kt) {
    gll16(Ap + (size_t)(tid >> 2) * I_ + kt * 32 + (tid & 3) * 8, As + (tid & 448) * 8);
  };
  auto ib = [&](float* Bf, int kt) {
    gll16f(Bp + (size_t)(kt * 32 + (tid >> 4)) * H_ + n0 + (tid & 15) * 4,
           Bf + (tid & 448) * 4);
  };
  pipe4g<I_ / 32>(ia, ib, A0, A1, A2, A3, F0, F1, F2, F3, Bb, acc);
#pragma unroll
  for (int m = 0; m < 2; ++m)
#pragma unroll
    for (int n = 0; n < 2; ++n) {
      f32x4 a = acc[m][n];
#pragma unroll
      for (int r = 0; r < 4; ++r) {
        int row = EPI_ROW(m, r);
        if (row >= gmax) continue;
        int col = EPI_COL(n);
        int slot = slot0 + row;
        float wgt = wslot[slot];
        int tk = tok[slot];
        atomicAdd(&moe[(size_t)tk * H_ + n0 + col], a[r] * wgt);
      }
    }
}

extern "C" void kernel_launch(void* const* d_in, const int* in_sizes, int n_in,
                              void* d_out, int out_size, void* d_ws, size_t ws_size,
                              hipStream_t stream) {
  const float* hs    = (const float*)d_in[0];
  const int*   pos   = (const int*)d_in[1];
  const float* wn1   = (const float*)d_in[2];
  const float* wn2   = (const float*)d_in[3];
  const float* wqkv  = (const float*)d_in[4];
  const float* wqn   = (const float*)d_in[5];
  const float* wkn   = (const float*)d_in[6];
  const float* wo    = (const float*)d_in[7];
  const float* wrt   = (const float*)d_in[8];
  const float* wg    = (const float*)d_in[9];
  const float* wu    = (const float*)d_in[10];
  const float* wd    = (const float*)d_in[11];
  float* out = (float*)d_out;
  float* moe_out = out;                       // T*H fp32
  float* resid   = out + (size_t)T_ * H_;     // T*H fp32

  char* ws = (char*)d_ws;
  size_t off = 0;
  auto alloc = [&](size_t bytes) { size_t r = off; off = (off + bytes + 255) & ~(size_t)255; return r; };
  u16*   h1    = (u16*)  (ws + alloc((size_t)T_ * H_ * 2));
  float* qkv   = (float*)(ws + alloc((size_t)T_ * QKVN * 4));
  u16*   q     = (u16*)  (ws + alloc((size_t)T_ * NH_ * HD_ * 2));
  u16*   kb    = (u16*)  (ws + alloc((size_t)NKV_ * T_ * HD_ * 2));
  u16*   vT    = (u16*)  (ws + alloc((size_t)NKV_ * HD_ * T_ * 2));
  u16*   ctx   = (u16*)  (ws + alloc((size_t)T_ * NH_ * HD_ * 2));
  float* opart = (float*)(ws + alloc((size_t)4 * T_ * NH_ * HD_ * 4));
  float* lpart = (float*)(ws + alloc((size_t)4 * NH_ * T_ * 4));
  float* h2f   = (float*)(ws + alloc((size_t)T_ * H_ * 4));
  u16*   h2b   = (u16*)  (ws + alloc((size_t)T_ * H_ * 2));
  u16*   act   = (u16*)  (ws + alloc((size_t)(2 * T_ + 256) * I_ * 2));
  int*   topi  = (int*)  (ws + alloc((size_t)T_ * 2 * 4));
  float* topw  = (float*)(ws + alloc((size_t)T_ * 2 * 4));
  int*   cnt   = (int*)  (ws + alloc(32 * 4));
  int*   posc  = cnt + 16;
  int*   base  = (int*)  (ws + alloc(32 * 4));
  int*   tok   = (int*)  (ws + alloc((size_t)(2 * T_ + 128) * 4));
  float* wsl   = (float*)(ws + alloc((size_t)(2 * T_ + 128) * 4));
  (void)ws_size; (void)in_sizes; (void)n_in; (void)out_size;

  hipMemsetAsync(moe_out, 0, (size_t)T_ * H_ * 4, stream);
  hipMemsetAsync(cnt, 0, 32 * 4, stream);

  k_rms1<<<T_, 256, 0, stream>>>(hs, wn1, h1);
  k_qkv<<<dim3(QKVN / 64, T_ / 128), 512, 0, stream>>>(h1, wqkv, qkv);
  k_qkrope<<<T_, 256, 0, stream>>>(qkv, pos, wqn, wkn, q, kb, vT);
  k_fattn<<<dim3(NH_, T_ / 64, 4), 256, 0, stream>>>(q, kb, vT, opart, lpart);
  k_attnfin<<<T_, 256, 0, stream>>>(opart, lpart, ctx);
  k_wo<<<dim3(H_ / 64, T_ / 128), 512, 0, stream>>>(ctx, wo, hs, resid);
  k_rms2<<<T_, 256, 0, stream>>>(resid, wn2, h2f, h2b);
  k_router<<<T_, 256, 0, stream>>>(h2f, wrt, topi, topw, cnt);
  k_scan<<<1, 64, 0, stream>>>(cnt, base);
  k_assign<<<4, 256, 0, stream>>>(topi, topw, base, posc, tok, wsl);
  k_gateup<<<dim3(E_, I_ / 32, T_ / 128), 512, 0, stream>>>(h2b, wg, wu, cnt, base, tok, act);
  k_down<<<dim3(H_ / 64, E_, T_ / 128), 512, 0, stream>>>(act, wd, cnt, base, tok, wsl, moe_out);
}

// Round 21
// 324.334 us; speedup vs baseline: 1.0814x; 1.0814x over previous
//
#include <hip/hip_runtime.h>

#define T_    1024
#define H_    2048
#define NH_   16
#define NKV_  4
#define HD_   128
#define E_    16
#define I_    768
#define QKVN  3072

typedef __attribute__((ext_vector_type(8))) short  short8;
typedef __attribute__((ext_vector_type(4))) float  f32x4;
typedef unsigned short u16;

#define LDPA 32   // gll-staged bf16 tiles: LINEAR layout required (m104), 64B rows
#define LDPB 40   // fp32->bf16 reg-staged B tiles: padded, conflict-free

__device__ inline u16 f2bf(float f) {
  unsigned u = __builtin_bit_cast(unsigned, f);
  return (u16)((u + 0x7fffu + ((u >> 16) & 1u)) >> 16);
}
__device__ inline float bf2f(u16 h) {
  unsigned u = ((unsigned)h) << 16;
  return __builtin_bit_cast(float, u);
}

// async global->LDS, 16B/lane (m97 lever). LDS dest = wave-uniform base + lane*16.
__device__ inline void gll16(const u16* g, u16* l) {
  __builtin_amdgcn_global_load_lds(
      (const __attribute__((address_space(1))) void*)g,
      (__attribute__((address_space(3))) void*)l, 16, 0, 0);
}

__device__ inline float blk_sum(float v, float* lds) {
#pragma unroll
  for (int o = 32; o; o >>= 1) v += __shfl_down(v, o);
  int w = threadIdx.x >> 6;
  __syncthreads();
  if ((threadIdx.x & 63) == 0) lds[w] = v;
  __syncthreads();
  float s = lds[0];
  int nw = blockDim.x >> 6;
  for (int i = 1; i < nw; ++i) s += lds[i];
  return s;
}

// -------- GEMM: 512 threads, 8 waves (4M x 2N), tile 128 x 64 x 32 (r15/r19 winner) --------

struct F4 { float v[4]; };    // B fp32: 64 cols x 32 k; n=tid&63, kh=(tid>>6)*4

__device__ inline void wrS(u16* lds, const F4& r) {
  int n = threadIdx.x & 63, kh = (threadIdx.x >> 6) * 4;
  uint2 w;
  w.x = (unsigned)f2bf(r.v[0]) | ((unsigned)f2bf(r.v[1]) << 16);
  w.y = (unsigned)f2bf(r.v[2]) | ((unsigned)f2bf(r.v[3]) << 16);
  *(uint2*)(lds + n * LDPB + kh) = w;
}

template<int SA, int SB>
__device__ inline void mma2(const u16* As, const u16* Bs, f32x4 acc[2][2]) {
  const int lane = threadIdx.x & 63, wv = threadIdx.x >> 6;
  const int wr = wv >> 1, wc = wv & 1;
  const int kk = (lane >> 4) * 8, rr = lane & 15;
  short8 aF[2], bF[2];
#pragma unroll
  for (int m = 0; m < 2; ++m)
    aF[m] = *(const short8*)(As + (wr * 32 + m * 16 + rr) * SA + kk);
#pragma unroll
  for (int n = 0; n < 2; ++n)
    bF[n] = *(const short8*)(Bs + (wc * 32 + n * 16 + rr) * SB + kk);
#pragma unroll
  for (int m = 0; m < 2; ++m)
#pragma unroll
    for (int n = 0; n < 2; ++n)
      acc[m][n] = __builtin_amdgcn_mfma_f32_16x16x32_bf16(aF[m], bF[n], acc[m][n], 0, 0, 0);
}

#define ZERO_ACC(acc) do { \
  _Pragma("unroll") for (int m_ = 0; m_ < 2; ++m_) \
  _Pragma("unroll") for (int n_ = 0; n_ < 2; ++n_) acc[m_][n_] = (f32x4){0.f,0.f,0.f,0.f}; \
} while (0)

#define EPI_ROW(m, r)  (((threadIdx.x >> 6) >> 1) * 32 + (m)*16 + (((threadIdx.x&63) >> 4) * 4) + (r))
#define EPI_COL(n)     ((((threadIdx.x >> 6) & 1) * 32) + (n)*16 + ((threadIdx.x&63) & 15))

// A via gll + B fp32 regs. NT even >= 4. __syncthreads drains vmcnt -> staged landed.
template<int NT, class GA, class LB>
__device__ inline void pipeGF(GA ga, LB lb, u16* A0, u16* B0, u16* A1, u16* B1,
                              f32x4 acc[2][2]) {
  F4 b0, b1;
  ga(A0, 0);
  lb(b0, 0); lb(b1, 1);
  wrS(B0, b0);
  if (NT > 2) lb(b0, 2);
#pragma unroll 1
  for (int kt = 0; kt < NT; kt += 2) {
    __syncthreads();
    ga(A1, kt + 1);
    wrS(B1, b1);
    if (kt + 3 < NT) lb(b1, kt + 3);
    mma2<LDPA, LDPB>(A0, B0, acc);
    __syncthreads();
    if (kt + 2 < NT) { ga(A0, kt + 2); wrS(B0, b0); }
    if (kt + 4 < NT) lb(b0, kt + 4);
    mma2<LDPA, LDPB>(A1, B1, acc);
  }
}

// ---------------- kernels ----------------

__global__ __launch_bounds__(256) void k_rms1(const float* x, const float* w, u16* out) {
  __shared__ float lds[4];
  int t = blockIdx.x, tid = threadIdx.x;
  float v[8]; float ss = 0.f;
#pragma unroll
  for (int i = 0; i < 8; ++i) { v[i] = x[(size_t)t * H_ + tid + 256 * i]; ss += v[i] * v[i]; }
  ss = blk_sum(ss, lds);
  float inv = rsqrtf(ss * (1.f / H_) + 1e-6f);
#pragma unroll
  for (int i = 0; i < 8; ++i)
    out[(size_t)t * H_ + tid + 256 * i] = f2bf(v[i] * inv * w[tid + 256 * i]);
}

// FUSED rms2 + router: one pass over resid; h2f buffer eliminated (router
// consumes the fp32 normed values straight from LDS). Saves 1 launch + 16 MB.
__global__ __launch_bounds__(256) void k_rms2rt(const float* x, const float* w,
                                                const float* wr_, u16* outb,
                                                int* topi, float* topw, int* cnt) {
  __shared__ float xs[H_];
  __shared__ float red[4][16];
  __shared__ float lg[16];
  __shared__ float lds[4];
  int t = blockIdx.x, tid = threadIdx.x;
  float v[8]; float ss = 0.f;
#pragma unroll
  for (int i = 0; i < 8; ++i) { v[i] = x[(size_t)t * H_ + tid + 256 * i]; ss += v[i] * v[i]; }
  ss = blk_sum(ss, lds);
  float inv = rsqrtf(ss * (1.f / H_) + 1e-6f);
#pragma unroll
  for (int i = 0; i < 8; ++i) {
    float r = v[i] * inv * w[tid + 256 * i];
    outb[(size_t)t * H_ + tid + 256 * i] = f2bf(r);
    xs[tid + 256 * i] = r;
  }
  __syncthreads();
  int e = tid & 15, p = tid >> 4;
  float s = 0.f;
  int b0 = p * 128;
  for (int i = 0; i < 128; ++i) s += xs[b0 + i] * wr_[(size_t)(b0 + i) * E_ + e];
  s += __shfl_down(s, 32);
  s += __shfl_down(s, 16);
  int lane = tid & 63, w64 = tid >> 6;
  if (lane < 16) red[w64][lane] = s;
  __syncthreads();
  if (tid < 16) lg[tid] = red[0][tid] + red[1][tid] + red[2][tid] + red[3][tid];
  __syncthreads();
  if (tid == 0) {
    float l1 = -1e30f; int e1 = 0;
    for (int i = 0; i < E_; ++i) if (lg[i] > l1) { l1 = lg[i]; e1 = i; }
    float l2 = -1e30f; int e2 = 0;
    for (int i = 0; i < E_; ++i) if (i != e1 && lg[i] > l2) { l2 = lg[i]; e2 = i; }
    float d = __expf(l2 - l1);
    float w1 = 1.f / (1.f + d), w2 = d / (1.f + d);
    topi[2 * t] = e1; topi[2 * t + 1] = e2;
    topw[2 * t] = w1; topw[2 * t + 1] = w2;
    atomicAdd(&cnt[e1], 1);
    atomicAdd(&cnt[e2], 1);
  }
}

// qkv: [1024 x 3072 x 2048]. grid (48, 8)
__global__ __launch_bounds__(512) void k_qkv(const u16* h1, const float* wqkv, float* qkv) {
  __shared__ __align__(16) u16 A0[128 * LDPA], A1[128 * LDPA];
  __shared__ __align__(16) u16 B0[64 * LDPB], B1[64 * LDPB];
  int bn = blockIdx.x, bm = blockIdx.y;
  f32x4 acc[2][2]; ZERO_ACC(acc);
  auto ga = [&](u16* As, int kt) {
    gll16(h1 + (size_t)(bm * 128 + (threadIdx.x >> 2)) * H_ + kt * 32 + (threadIdx.x & 3) * 8,
          As + (threadIdx.x & 448) * 8);
  };
  auto lb = [&](F4& r, int kt) {
    int n = threadIdx.x & 63, kh = (threadIdx.x >> 6) * 4;
    const float* src = wqkv + (size_t)(kt * 32 + kh) * QKVN + bn * 64 + n;
#pragma unroll
    for (int j = 0; j < 4; ++j) r.v[j] = src[(size_t)j * QKVN];
  };
  pipeGF<H_ / 32>(ga, lb, A0, B0, A1, B1, acc);
#pragma unroll
  for (int m = 0; m < 2; ++m)
#pragma unroll
    for (int n = 0; n < 2; ++n) {
      f32x4 a = acc[m][n];
#pragma unroll
      for (int r = 0; r < 4; ++r)
        qkv[(size_t)(bm * 128 + EPI_ROW(m, r)) * QKVN + bn * 64 + EPI_COL(n)] = a[r];
    }
}

__global__ __launch_bounds__(256) void k_qkrope(const float* qkv, const int* pos,
                                                const float* wq, const float* wk,
                                                u16* q, u16* kk, u16* vT) {
  __shared__ float cs[64], sn[64];
  int t = blockIdx.x, tid = threadIdx.x, lane = tid & 63, w = tid >> 6;
  if (tid < 64) {
    float fr = expf(-((float)tid / 64.f) * 9.210340371976184f);
    float ang = (float)pos[t] * fr;
    float s_, c_; sincosf(ang, &s_, &c_);
    cs[tid] = c_; sn[tid] = s_;
  }
  __syncthreads();
  const float* row = qkv + (size_t)t * QKVN;
  for (int h = w; h < NH_; h += 4) {
    float x1 = row[h * 128 + lane], x2 = row[h * 128 + 64 + lane];
    float ss = x1 * x1 + x2 * x2;
#pragma unroll
    for (int o = 32; o; o >>= 1) ss += __shfl_down(ss, o);
    ss = __shfl(ss, 0);
    float inv = rsqrtf(ss * (1.f / HD_) + 1e-6f);
    float n1 = x1 * inv * wq[lane], n2 = x2 * inv * wq[64 + lane];
    float o1 = n1 * cs[lane] - n2 * sn[lane];
    float o2 = n2 * cs[lane] + n1 * sn[lane];
    q[(size_t)t * (NH_ * HD_) + h * 128 + lane] = f2bf(o1);
    q[(size_t)t * (NH_ * HD_) + h * 128 + 64 + lane] = f2bf(o2);
  }
  if (w < NKV_) {
    int h = w;
    float x1 = row[2048 + h * 128 + lane], x2 = row[2048 + h * 128 + 64 + lane];
    float ss = x1 * x1 + x2 * x2;
#pragma unroll
    for (int o = 32; o; o >>= 1) ss += __shfl_down(ss, o);
    ss = __shfl(ss, 0);
    float inv = rsqrtf(ss * (1.f / HD_) + 1e-6f);
    float n1 = x1 * inv * wk[lane], n2 = x2 * inv * wk[64 + lane];
    float o1 = n1 * cs[lane] - n2 * sn[lane];
    float o2 = n2 * cs[lane] + n1 * sn[lane];
    kk[((size_t)h * T_ + t) * HD_ + lane] = f2bf(o1);
    kk[((size_t)h * T_ + t) * HD_ + 64 + lane] = f2bf(o2);
    float v1 = row[2560 + h * 128 + lane], v2 = row[2560 + h * 128 + 64 + lane];
    vT[((size_t)(h * 128 + lane)) * T_ + t] = f2bf(v1);
    vT[((size_t)(h * 128 + 64 + lane)) * T_ + t] = f2bf(v2);
  }
}

// Fused attention with kv-split x4 (r17/r19-proven). No max-subtraction needed
// (q,k RMSNorm'd -> |q.k| <= 128 -> scaled scores <= 11.32 -> exp fp32-safe).
__global__ __launch_bounds__(256) void k_fattn(const u16* q, const u16* kb,
                                               const u16* vT, float* opart, float* lpart) {
  __shared__ __align__(16) u16 Ks[64 * 136];
  __shared__ __align__(16) u16 Vs[128 * 72];
  __shared__ __align__(16) u16 Ps[4 * 16 * 72];
  int h = blockIdx.x, qt = blockIdx.y, kvs = blockIdx.z;
  int tid = threadIdx.x, lane = tid & 63, wv = tid >> 6;
  int rr = lane & 15, kk = (lane >> 4) * 8;
  const u16* kbh = kb + (size_t)(h >> 2) * T_ * HD_;
  const u16* vTh = vT + (size_t)(h >> 2) * HD_ * T_;
  int q0 = qt * 64 + wv * 16;
  short8 qf[4];
#pragma unroll
  for (int ks = 0; ks < 4; ++ks)
    qf[ks] = *(const short8*)(q + (size_t)(q0 + rr) * (NH_ * HD_) + h * 128 + ks * 32 + kk);
  f32x4 oacc[8];
#pragma unroll
  for (int i = 0; i < 8; ++i) oacc[i] = (f32x4){0.f, 0.f, 0.f, 0.f};
  float lsum[4] = {0.f, 0.f, 0.f, 0.f};
  const float scale = 0.08838834764831845f;
  u16* Pw = Ps + wv * 16 * 72;
#pragma unroll 1
  for (int kv = kvs * 4; kv < kvs * 4 + 4; ++kv) {
    __syncthreads();
    {
      uint4 kreg[4];
#pragma unroll
      for (int i = 0; i < 4; ++i) {
        int c = tid + 256 * i;
        kreg[i] = *(const uint4*)(kbh + (size_t)(kv * 64 + (c >> 4)) * HD_ + (c & 15) * 8);
      }
#pragma unroll
      for (int i = 0; i < 4; ++i) {
        int c = tid + 256 * i;
        *(uint4*)(Ks + (c >> 4) * 136 + (c & 15) * 8) = kreg[i];
      }
    }
    {
      uint4 vreg[4];
#pragma unroll
      for (int i = 0; i < 4; ++i) {
        int c = tid + 256 * i;
        vreg[i] = *(const uint4*)(vTh + (size_t)(c >> 3) * T_ + kv * 64 + (c & 7) * 8);
      }
#pragma unroll
      for (int i = 0; i < 4; ++i) {
        int c = tid + 256 * i;
        *(uint4*)(Vs + (c >> 3) * 72 + (c & 7) * 8) = vreg[i];
      }
    }
    __syncthreads();
    f32x4 sacc[4];
#pragma unroll
    for (int nf = 0; nf < 4; ++nf) sacc[nf] = (f32x4){0.f, 0.f, 0.f, 0.f};
#pragma unroll
    for (int ks = 0; ks < 4; ++ks)
#pragma unroll
      for (int nf = 0; nf < 4; ++nf) {
        short8 bF = *(const short8*)(Ks + (nf * 16 + rr) * 136 + ks * 32 + kk);
        sacc[nf] = __builtin_amdgcn_mfma_f32_16x16x32_bf16(qf[ks], bF, sacc[nf], 0, 0, 0);
      }
#pragma unroll
    for (int nf = 0; nf < 4; ++nf)
#pragma unroll
      for (int r = 0; r < 4; ++r) {
        float p = __expf(sacc[nf][r] * scale);
        lsum[r] += p;
        Pw[((lane >> 4) * 4 + r) * 72 + nf * 16 + rr] = f2bf(p);
      }
#pragma unroll
    for (int ks2 = 0; ks2 < 2; ++ks2) {
      short8 pa = *(const short8*)(Pw + rr * 72 + ks2 * 32 + kk);
#pragma unroll
      for (int nd = 0; nd < 8; ++nd) {
        short8 bV = *(const short8*)(Vs + (nd * 16 + rr) * 72 + ks2 * 32 + kk);
        oacc[nd] = __builtin_amdgcn_mfma_f32_16x16x32_bf16(pa, bV, oacc[nd], 0, 0, 0);
      }
    }
  }
#pragma unroll
  for (int r = 0; r < 4; ++r) {
#pragma unroll
    for (int o = 1; o < 16; o <<= 1) lsum[r] += __shfl_xor(lsum[r], o);
  }
  if ((lane & 15) == 0) {
#pragma unroll
    for (int r = 0; r < 4; ++r)
      lpart[((size_t)kvs * NH_ + h) * T_ + q0 + (lane >> 4) * 4 + r] = lsum[r];
  }
  float* op = opart + (size_t)kvs * T_ * (NH_ * HD_);
#pragma unroll
  for (int nd = 0; nd < 8; ++nd)
#pragma unroll
    for (int r = 0; r < 4; ++r)
      op[(size_t)(q0 + (lane >> 4) * 4 + r) * (NH_ * HD_) + h * 128 + nd * 16 + rr] =
          oacc[nd][r];
}

__global__ __launch_bounds__(256) void k_attnfin(const float* opart, const float* lpart,
                                                 u16* ctx) {
  int t = blockIdx.x, tid = threadIdx.x;
#pragma unroll
  for (int i = 0; i < 8; ++i) {
    int idx = tid + 256 * i;
    int h = idx >> 7;
    float l = 0.f, o = 0.f;
#pragma unroll
    for (int s = 0; s < 4; ++s) {
      l += lpart[((size_t)s * NH_ + h) * T_ + t];
      o += opart[(size_t)s * T_ * (NH_ * HD_) + (size_t)t * (NH_ * HD_) + idx];
    }
    ctx[(size_t)t * (NH_ * HD_) + idx] = f2bf(o / l);
  }
}

// wo: [1024 x 2048 x 2048]. grid (32, 8)
__global__ __launch_bounds__(512) void k_wo(const u16* ctx, const float* wo,
                                            const float* hs, float* resid) {
  __shared__ __align__(16) u16 A0[128 * LDPA], A1[128 * LDPA];
  __shared__ __align__(16) u16 B0[64 * LDPB], B1[64 * LDPB];
  int bn = blockIdx.x, bm = blockIdx.y;
  f32x4 acc[2][2]; ZERO_ACC(acc);
  auto ga = [&](u16* As, int kt) {
    gll16(ctx + (size_t)(bm * 128 + (threadIdx.x >> 2)) * H_ + kt * 32 + (threadIdx.x & 3) * 8,
          As + (threadIdx.x & 448) * 8);
  };
  auto lb = [&](F4& r, int kt) {
    int n = threadIdx.x & 63, kh = (threadIdx.x >> 6) * 4;
    const float* src = wo + (size_t)(kt * 32 + kh) * H_ + bn * 64 + n;
#pragma unroll
    for (int j = 0; j < 4; ++j) r.v[j] = src[(size_t)j * H_];
  };
  pipeGF<H_ / 32>(ga, lb, A0, B0, A1, B1, acc);
#pragma unroll
  for (int m = 0; m < 2; ++m)
#pragma unroll
    for (int n = 0; n < 2; ++n) {
      f32x4 a = acc[m][n];
#pragma unroll
      for (int r = 0; r < 4; ++r) {
        size_t idx = (size_t)(bm * 128 + EPI_ROW(m, r)) * H_ + bn * 64 + EPI_COL(n);
        resid[idx] = a[r] + hs[idx];
      }
    }
}

// FUSED scan + assign: 1 block. Saves 1 launch.
__global__ __launch_bounds__(256) void k_scanassign(const int* cnt, int* basearr, int* posc,
                                                    const int* topi, const float* topw,
                                                    int* tok, float* wslot) {
  __shared__ int bs[E_ + 1];
  if (threadIdx.x == 0) {
    int b = 0;
    for (int e = 0; e < E_; ++e) { bs[e] = b; basearr[e] = b; b += cnt[e]; }
    bs[E_] = b; basearr[E_] = b;
  }
  __syncthreads();
  for (int t = threadIdx.x; t < T_; t += 256) {
#pragma unroll
    for (int j = 0; j < 2; ++j) {
      int e = topi[2 * t + j];
      int p = atomicAdd(&posc[e], 1);
      int s = bs[e] + p;
      tok[s] = t;
      wslot[s] = topw[2 * t + j];
    }
  }
}

// gateup: 128 tokens x 32 out cols (64 LDS cols interleave g|u per 16-col group).
__global__ __launch_bounds__(512) void k_gateup(const u16* h2b,
                                                const float* wg, const float* wu,
                                                const int* cnt, const int* basearr, const int* tok,
                                                u16* act) {
  __shared__ __align__(16) u16 A0[128 * LDPA], A1[128 * LDPA];
  __shared__ __align__(16) u16 B0[64 * LDPB], B1[64 * LDPB];
  __shared__ int gat_s[128];
  int e = blockIdx.x;
  int c = cnt[e];
  int mt = blockIdx.z;
  if (mt * 128 >= c) return;
  int basee = basearr[e];
  int gmax = c - mt * 128;
  int n0 = blockIdx.y * 32;
  int tid = threadIdx.x;
  if (tid < 128) {
    int r = mt * 128 + tid;
    gat_s[tid] = (r < c) ? tok[basee + r] : tok[basee];
  }
  __syncthreads();
  int grow = gat_s[tid >> 2];
  const float* Bg = wg + (size_t)e * H_ * I_;
  const float* Bu = wu + (size_t)e * H_ * I_;
  f32x4 acc[2][2]; ZERO_ACC(acc);
  auto ga = [&](u16* As, int kt) {
    gll16(h2b + (size_t)grow * H_ + kt * 32 + (tid & 3) * 8, As + (tid & 448) * 8);
  };
  auto lb = [&](F4& r, int kt) {
    int cidx = tid & 63, kh = (tid >> 6) * 4;
    int fn = cidx >> 4;
    const float* base = (fn & 1) ? Bu : Bg;
    int col = n0 + (fn >> 1) * 16 + (cidx & 15);
    const float* src = base + (size_t)(kt * 32 + kh) * I_ + col;
#pragma unroll
    for (int j = 0; j < 4; ++j) r.v[j] = src[(size_t)j * I_];
  };
  pipeGF<H_ / 32>(ga, lb, A0, B0, A1, B1, acc);
  int slot0 = basee + mt * 128;
  int col = n0 + ((tid >> 6) & 1) * 16 + ((tid & 63) & 15);
#pragma unroll
  for (int m = 0; m < 2; ++m) {
#pragma unroll
    for (int r = 0; r < 4; ++r) {
      int row = EPI_ROW(m, r);
      if (row >= gmax) continue;
      float g = acc[m][0][r], u = acc[m][1][r];
      float sg = g / (1.f + __expf(-g));
      act[(size_t)(slot0 + row) * I_ + col] = f2bf(sg * u);
    }
  }
}

// down: [slots x 2048 x 768]. grid (32, 16, 8)
__global__ __launch_bounds__(512) void k_down(const u16* act, const float* wd,
                                              const int* cnt, const int* basearr,
                                              const int* tok, const float* wslot,
                                              float* moe) {
  __shared__ __align__(16) u16 A0[128 * LDPA], A1[128 * LDPA];
  __shared__ __align__(16) u16 B0[64 * LDPB], B1[64 * LDPB];
  int e = blockIdx.y;
  int c = cnt[e];
  int mt = blockIdx.z;
  if (mt * 128 >= c) return;
  int basee = basearr[e];
  int gmax = c - mt * 128;
  int slot0 = basee + mt * 128;
  int n0 = blockIdx.x * 64;
  const u16* Ap = act + (size_t)slot0 * I_;
  const float* Bp = wd + (size_t)e * I_ * H_;
  f32x4 acc[2][2]; ZERO_ACC(acc);
  auto ga = [&](u16* As, int kt) {
    gll16(Ap + (size_t)(threadIdx.x >> 2) * I_ + kt * 32 + (threadIdx.x & 3) * 8,
          As + (threadIdx.x & 448) * 8);
  };
  auto lb = [&](F4& r, int kt) {
    int n = threadIdx.x & 63, kh = (threadIdx.x >> 6) * 4;
    const float* src = Bp + (size_t)(kt * 32 + kh) * H_ + n0 + n;
#pragma unroll
    for (int j = 0; j < 4; ++j) r.v[j] = src[(size_t)j * H_];
  };
  pipeGF<I_ / 32>(ga, lb, A0, B0, A1, B1, acc);
#pragma unroll
  for (int m = 0; m < 2; ++m)
#pragma unroll
    for (int n = 0; n < 2; ++n) {
      f32x4 a = acc[m][n];
#pragma unroll
      for (int r = 0; r < 4; ++r) {
        int row = EPI_ROW(m, r);
        if (row >= gmax) continue;
        int col = EPI_COL(n);
        int slot = slot0 + row;
        float wgt = wslot[slot];
        int tk = tok[slot];
        atomicAdd(&moe[(size_t)tk * H_ + n0 + col], a[r] * wgt);
      }
    }
}

extern "C" void kernel_launch(void* const* d_in, const int* in_sizes, int n_in,
                              void* d_out, int out_size, void* d_ws, size_t ws_size,
                              hipStream_t stream) {
  const float* hs    = (const float*)d_in[0];
  const int*   pos   = (const int*)d_in[1];
  const float* wn1   = (const float*)d_in[2];
  const float* wn2   = (const float*)d_in[3];
  const float* wqkv  = (const float*)d_in[4];
  const float* wqn   = (const float*)d_in[5];
  const float* wkn   = (const float*)d_in[6];
  const float* wo    = (const float*)d_in[7];
  const float* wrt   = (const float*)d_in[8];
  const float* wg    = (const float*)d_in[9];
  const float* wu    = (const float*)d_in[10];
  const float* wd    = (const float*)d_in[11];
  float* out = (float*)d_out;
  float* moe_out = out;                       // T*H fp32
  float* resid   = out + (size_t)T_ * H_;     // T*H fp32

  char* ws = (char*)d_ws;
  size_t off = 0;
  auto alloc = [&](size_t bytes) { size_t r = off; off = (off + bytes + 255) & ~(size_t)255; return r; };
  u16*   h1    = (u16*)  (ws + alloc((size_t)T_ * H_ * 2));
  float* qkv   = (float*)(ws + alloc((size_t)T_ * QKVN * 4));
  u16*   q     = (u16*)  (ws + alloc((size_t)T_ * NH_ * HD_ * 2));
  u16*   kb    = (u16*)  (ws + alloc((size_t)NKV_ * T_ * HD_ * 2));
  u16*   vT    = (u16*)  (ws + alloc((size_t)NKV_ * HD_ * T_ * 2));
  u16*   ctx   = (u16*)  (ws + alloc((size_t)T_ * NH_ * HD_ * 2));
  float* opart = (float*)(ws + alloc((size_t)4 * T_ * NH_ * HD_ * 4));
  float* lpart = (float*)(ws + alloc((size_t)4 * NH_ * T_ * 4));
  u16*   h2b   = (u16*)  (ws + alloc((size_t)T_ * H_ * 2));
  u16*   act   = (u16*)  (ws + alloc((size_t)(2 * T_ + 256) * I_ * 2));
  int*   topi  = (int*)  (ws + alloc((size_t)T_ * 2 * 4));
  float* topw  = (float*)(ws + alloc((size_t)T_ * 2 * 4));
  int*   cnt   = (int*)  (ws + alloc(32 * 4));
  int*   posc  = cnt + 16;
  int*   base  = (int*)  (ws + alloc(32 * 4));
  int*   tok   = (int*)  (ws + alloc((size_t)(2 * T_ + 128) * 4));
  float* wsl   = (float*)(ws + alloc((size_t)(2 * T_ + 128) * 4));
  (void)ws_size; (void)in_sizes; (void)n_in; (void)out_size;

  hipMemsetAsync(moe_out, 0, (size_t)T_ * H_ * 4, stream);
  hipMemsetAsync(cnt, 0, 32 * 4, stream);

  k_rms1<<<T_, 256, 0, stream>>>(hs, wn1, h1);
  k_qkv<<<dim3(QKVN / 64, T_ / 128), 512, 0, stream>>>(h1, wqkv, qkv);
  k_qkrope<<<T_, 256, 0, stream>>>(qkv, pos, wqn, wkn, q, kb, vT);
  k_fattn<<<dim3(NH_, T_ / 64, 4), 256, 0, stream>>>(q, kb, vT, opart, lpart);
  k_attnfin<<<T_, 256, 0, stream>>>(opart, lpart, ctx);
  k_wo<<<dim3(H_ / 64, T_ / 128), 512, 0, stream>>>(ctx, wo, hs, resid);
  k_rms2rt<<<T_, 256, 0, stream>>>(resid, wn2, wrt, h2b, topi, topw, cnt);
  k_scanassign<<<1, 256, 0, stream>>>(cnt, base, posc, topi, topw, tok, wsl);
  k_gateup<<<dim3(E_, I_ / 32, T_ / 128), 512, 0, stream>>>(h2b, wg, wu, cnt, base, tok, act);
  k_down<<<dim3(H_ / 64, E_, T_ / 128), 512, 0, stream>>>(act, wd, cnt, base, tok, wsl, moe_out);
}